// Round 4
// baseline (188.956 us; speedup 1.0000x reference)
//
#include <hip/hip_runtime.h>
#include <hip/hip_cooperative_groups.h>
#include <stdint.h>

#define NROWS 8192
#define KX    2048      // N*M
#define KA    2112      // KX + NF (augmented K)
#define NF    64
#define DD    2016
#define WCOLS 2080      // NF + DD
#define ODIM  1024
#define BN_EPS 1e-5f

#define A1_OT 32        // o-tile for build_a1
#define A2_DC 8         // d-chunks for build_a2
#define A2_DPC 252      // DD / A2_DC
#define A2_OT 16        // o-tile for build_a2

using f32x4  = __attribute__((ext_vector_type(4))) float;
using bf16x8 = __attribute__((ext_vector_type(8))) short;

__device__ __forceinline__ short f2bf(float x) {
    uint32_t u = __float_as_uint(x);
    uint32_t r = (u + 0x7FFFu + ((u >> 16) & 1u)) >> 16;   // RNE to bf16
    return (short)r;
}

__device__ __forceinline__ void gload16(const void* g, void* l) {
    __builtin_amdgcn_global_load_lds(
        (const __attribute__((address_space(1))) uint32_t*)g,
        (__attribute__((address_space(3))) uint32_t*)l, 16, 0, 0);
}

// ---------------------------------------------------------------------------
// Kernel 1: convert X (fp32) -> bf16 into augmented Xa[8192][2112];
// cols [0,2048) = bf16(x); cols [2048,2112) = bf16(sum_m x^2 - 32) per field.
// (The -32 centering and the BN bias-cancellation are exact under BN's
//  per-column mean subtraction.)
// ---------------------------------------------------------------------------
__global__ __launch_bounds__(256) void convert_x(const float* __restrict__ X,
                                                 short* __restrict__ Xa) {
    const int row = blockIdx.x;
    const int t = threadIdx.x;
    const float4* xr = reinterpret_cast<const float4*>(X + (size_t)row * KX);
    float4 v0 = xr[t * 2];
    float4 v1 = xr[t * 2 + 1];
    bf16x8 s;
    s[0] = f2bf(v0.x); s[1] = f2bf(v0.y); s[2] = f2bf(v0.z); s[3] = f2bf(v0.w);
    s[4] = f2bf(v1.x); s[5] = f2bf(v1.y); s[6] = f2bf(v1.z); s[7] = f2bf(v1.w);
    short* outr = Xa + (size_t)row * KA;
    reinterpret_cast<bf16x8*>(outr)[t] = s;
    float sq = v0.x*v0.x + v0.y*v0.y + v0.z*v0.z + v0.w*v0.w
             + v1.x*v1.x + v1.y*v1.y + v1.z*v1.z + v1.w*v1.w;
    sq += __shfl_xor(sq, 1);
    sq += __shfl_xor(sq, 2);
    if ((t & 3) == 0) outr[KX + (t >> 2)] = f2bf(sq - 32.0f);  // centered
}

// ---------------------------------------------------------------------------
// Kernel 2: A1[o][k] = sum_{d<64} Wa[o][d] * Wz[d][k] -> bf16 Aw[o][0..2048)
// ---------------------------------------------------------------------------
__global__ __launch_bounds__(256) void build_a1(const float* __restrict__ Wa,
                                                const float* __restrict__ Wz,
                                                short* __restrict__ Aw) {
    const int k = blockIdx.x * 256 + threadIdx.x;
    const int o0 = blockIdx.y * A1_OT;
    float wz[64];
#pragma unroll
    for (int d = 0; d < 64; ++d) wz[d] = Wz[(size_t)d * KX + k];
    for (int o = o0; o < o0 + A1_OT; ++o) {
        const float* war = Wa + (size_t)o * WCOLS;
        float acc = 0.f;
#pragma unroll
        for (int d = 0; d < 64; ++d) acc += war[d] * wz[d];
        Aw[(size_t)o * KA + k] = f2bf(acc);
    }
}

// ---------------------------------------------------------------------------
// Kernel 3a: A2 partials[chunk][o][n] = sum_{d in chunk} Wa2[o][d]*theta[d][n]^2
// ---------------------------------------------------------------------------
__global__ __launch_bounds__(256) void build_a2(const float* __restrict__ Wa,
                                                const float* __restrict__ theta,
                                                float* __restrict__ partials) {
    const int n = threadIdx.x & 63;
    const int g = threadIdx.x >> 6;
    const int o0 = blockIdx.y * A2_OT;
    const int d0 = blockIdx.x * A2_DPC;
    float acc[A2_OT];
#pragma unroll
    for (int j = 0; j < A2_OT; ++j) acc[j] = 0.f;
    for (int i = g; i < A2_DPC; i += 4) {
        const int d = d0 + i;
        float th = theta[(size_t)d * NF + n];
        float th2 = th * th;
#pragma unroll
        for (int j = 0; j < A2_OT; ++j)
            acc[j] += Wa[(size_t)(o0 + j) * WCOLS + NF + d] * th2;
    }
    __shared__ float red[4][A2_OT][64];
#pragma unroll
    for (int j = 0; j < A2_OT; ++j) red[g][j][n] = acc[j];
    __syncthreads();
    const int t = threadIdx.x;
#pragma unroll
    for (int k = 0; k < A2_OT * 64 / 256; ++k) {
        const int idx = t + k * 256;
        const int ol = idx >> 6, nn = idx & 63;
        float s = red[0][ol][nn] + red[1][ol][nn] + red[2][ol][nn] + red[3][ol][nn];
        partials[((size_t)blockIdx.x * ODIM + o0 + ol) * NF + nn] = s;
    }
}

// Kernel 3b: reduce A2_DC partials -> bf16 Aw cols [2048,2112)
__global__ __launch_bounds__(256) void a2_reduce(const float* __restrict__ partials,
                                                 short* __restrict__ Aw) {
    const int idx = blockIdx.x * 256 + threadIdx.x;   // o*64+n
    const int o = idx >> 6, n = idx & 63;
    float s = 0.f;
#pragma unroll
    for (int c = 0; c < A2_DC; ++c)
        s += partials[((size_t)c * ODIM + o) * NF + n];
    Aw[(size_t)o * KA + KX + n] = f2bf(s);
}

// ---------------------------------------------------------------------------
// Kernel 4: cooperative GEMM + full BN.
// K-loop: round-2's proven single-buffer 2-barrier structure (678 TF).
// Epilogue: column sum/sumsq atomics -> grid.sync() -> normalize in-register
// -> single C write.  Bias is dropped (column-constant, cancels under BN).
// grid = 64x8 = 512 blocks = exactly 2 blocks/CU (co-resident:
// 16 KiB LDS x2 = 32 <= 160 KiB; __launch_bounds__(256,2) caps VGPR).
// ---------------------------------------------------------------------------
__global__ __launch_bounds__(256, 2) void gemm_bn(const short* __restrict__ Xa,
                                                  const short* __restrict__ Aw,
                                                  float* __restrict__ C,
                                                  float* __restrict__ sums,
                                                  const float* __restrict__ gamma,
                                                  const float* __restrict__ beta) {
    __shared__ __align__(16) short As[128 * 32];
    __shared__ __align__(16) short Bs[128 * 32];
    const int tid  = threadIdx.x;
    const int lane = tid & 63;
    const int wid  = tid >> 6;
    const int wr = wid >> 1, wc = wid & 1;
    const int bm = blockIdx.x * 128;
    const int bn = blockIdx.y * 128;

    f32x4 acc[4][4] = {};

    // Staging: chunk c (16B) at LDS pos c holds global slot q = (c&3) ^ ((r>>1)&3)
    const int c0 = tid, c1 = tid + 256;
    const int r0 = c0 >> 2, q0 = (c0 & 3) ^ ((r0 >> 1) & 3);
    const int r1 = c1 >> 2, q1 = (c1 & 3) ^ ((r1 >> 1) & 3);
    const short* gA0 = Xa + (size_t)(bm + r0) * KA + q0 * 8;
    const short* gA1 = Xa + (size_t)(bm + r1) * KA + q1 * 8;
    const short* gB0 = Aw + (size_t)(bn + r0) * KA + q0 * 8;
    const short* gB1 = Aw + (size_t)(bn + r1) * KA + q1 * 8;
    short* lA0 = As + c0 * 8;  short* lA1 = As + c1 * 8;
    short* lB0 = Bs + c0 * 8;  short* lB1 = Bs + c1 * 8;

    // Swizzled LDS read offsets
    const int lq = lane >> 4;
    int offA[4], offB[4];
#pragma unroll
    for (int m = 0; m < 4; ++m) {
        int ra = wr * 64 + m * 16 + (lane & 15);
        offA[m] = ra * 32 + (lq ^ ((ra >> 1) & 3)) * 8;
        int rb = wc * 64 + m * 16 + (lane & 15);
        offB[m] = rb * 32 + (lq ^ ((rb >> 1) & 3)) * 8;
    }

    for (int kt = 0; kt < KA / 32; ++kt) {
        const int ko = kt * 32;
        gload16(gA0 + ko, lA0);
        gload16(gA1 + ko, lA1);
        gload16(gB0 + ko, lB0);
        gload16(gB1 + ko, lB1);
        __syncthreads();
        bf16x8 a[4], b[4];
#pragma unroll
        for (int m = 0; m < 4; ++m) a[m] = *reinterpret_cast<const bf16x8*>(As + offA[m]);
#pragma unroll
        for (int n = 0; n < 4; ++n) b[n] = *reinterpret_cast<const bf16x8*>(Bs + offB[n]);
#pragma unroll
        for (int m = 0; m < 4; ++m)
#pragma unroll
            for (int n = 0; n < 4; ++n)
                acc[m][n] = __builtin_amdgcn_mfma_f32_16x16x32_bf16(a[m], b[n], acc[m][n], 0, 0, 0);
        __syncthreads();
    }

    // ---- BN stage 1: column partials (C/D layout col=lane&15, row=(lane>>4)*4+reg)
    const int rlo = (lane >> 4) * 4;
    const int cl  = lane & 15;
#pragma unroll
    for (int n = 0; n < 4; ++n) {
        const int col = bn + wc * 64 + n * 16 + cl;
        float s = 0.f, q = 0.f;
#pragma unroll
        for (int m = 0; m < 4; ++m)
#pragma unroll
            for (int r2 = 0; r2 < 4; ++r2) {
                float v = acc[m][n][r2];
                s += v; q += v * v;
            }
        s += __shfl_xor(s, 16); s += __shfl_xor(s, 32);
        q += __shfl_xor(q, 16); q += __shfl_xor(q, 32);
        if (lane < 16) {
            atomicAdd(&sums[col], s);
            atomicAdd(&sums[ODIM + col], q);
        }
    }

    cooperative_groups::this_grid().sync();

    // ---- BN stage 2: normalize in-register, single C write
    const float inv = 1.0f / (float)NROWS;
#pragma unroll
    for (int n = 0; n < 4; ++n) {
        const int col = bn + wc * 64 + n * 16 + cl;
        const float mean = sums[col] * inv;
        const float var  = sums[ODIM + col] * inv - mean * mean;
        const float sc   = gamma[col] * rsqrtf(var + BN_EPS);
        const float sh   = beta[col] - mean * sc;
#pragma unroll
        for (int m = 0; m < 4; ++m) {
            const int rowb = bm + wr * 64 + m * 16 + rlo;
#pragma unroll
            for (int r2 = 0; r2 < 4; ++r2)
                C[(size_t)(rowb + r2) * ODIM + col] = acc[m][n][r2] * sc + sh;
        }
    }
}

// ---------------------------------------------------------------------------
extern "C" void kernel_launch(void* const* d_in, const int* in_sizes, int n_in,
                              void* d_out, int out_size, void* d_ws, size_t ws_size,
                              hipStream_t stream) {
    const float* X     = (const float*)d_in[0];
    const float* Wz    = (const float*)d_in[1];
    const float* theta = (const float*)d_in[2];
    const float* Wa    = (const float*)d_in[3];
    const float* gamma = (const float*)d_in[5];
    const float* beta  = (const float*)d_in[6];
    float* out = (float*)d_out;

    char* ws = (char*)d_ws;
    float* sums = (float*)ws;                                        // 2*1024 f32
    short* Xa = (short*)(ws + 16384);                                // 8192*2112 bf16
    short* Aw = (short*)(ws + 16384 + (size_t)NROWS * KA * 2);       // 1024*2112 bf16
    float* partials = (float*)(ws + 16384 + (size_t)NROWS * KA * 2
                                        + (size_t)ODIM * KA * 2);    // 8*1024*64 f32

    hipMemsetAsync(sums, 0, 2 * ODIM * sizeof(float), stream);
    convert_x<<<NROWS, 256, 0, stream>>>(X, Xa);
    build_a1<<<dim3(KX / 256, ODIM / A1_OT), 256, 0, stream>>>(Wa, Wz, Aw);
    build_a2<<<dim3(A2_DC, ODIM / A2_OT), 256, 0, stream>>>(Wa, theta, partials);
    a2_reduce<<<ODIM * NF / 256, 256, 0, stream>>>(partials, Aw);

    const short* Xa_c = Xa;
    const short* Aw_c = Aw;
    void* args[] = {(void*)&Xa_c, (void*)&Aw_c, (void*)&out, (void*)&sums,
                    (void*)&gamma, (void*)&beta};
    hipLaunchCooperativeKernel((const void*)gemm_bn,
                               dim3(NROWS / 128, ODIM / 128), dim3(256),
                               args, 0, stream);
}

// Round 6
// 117.239 us; speedup vs baseline: 1.6117x; 1.6117x over previous
//
#include <hip/hip_runtime.h>
#include <stdint.h>

#define NROWS 8192
#define KX    2048      // N*M
#define KA    2112      // KX + NF (augmented K)
#define NF    64
#define DD    2016
#define WCOLS 2080      // NF + DD
#define ODIM  1024
#define BN_EPS 1e-5f

#define A1_OT 32        // o-tile for build_a1
#define A2_DC 8         // d-chunks for build_a2
#define A2_DPC 252      // DD / A2_DC
#define A2_OT 16        // o-tile for build_a2

// prep grid layout: [0,8192) convert | [8192,8448) a1 | [8448,8960) a2
#define PREP_CONV 8192
#define PREP_A1   (PREP_CONV + 256)
#define PREP_A2   (PREP_A1 + 512)

using f32x4  = __attribute__((ext_vector_type(4))) float;
using bf16x8 = __attribute__((ext_vector_type(8))) short;

__device__ __forceinline__ short f2bf(float x) {
    uint32_t u = __float_as_uint(x);
    uint32_t r = (u + 0x7FFFu + ((u >> 16) & 1u)) >> 16;   // RNE to bf16
    return (short)r;
}

__device__ __forceinline__ void gload16(const void* g, void* l) {
    __builtin_amdgcn_global_load_lds(
        (const __attribute__((address_space(1))) uint32_t*)g,
        (__attribute__((address_space(3))) uint32_t*)l, 16, 0, 0);
}

// ---------------------------------------------------------------------------
// Kernel 1 (fused prep): three independent jobs split by blockIdx.x.
//  (a) convert X -> bf16 Xa with augmented (x_sq-32) cols  [8192 blocks]
//  (b) A1 = Wa[:, :64] @ Wz -> bf16 Aw cols [0,2048)       [256 blocks]
//  (c) A2 partials (8 d-chunks x 16-o tiles)               [512 blocks]
// ---------------------------------------------------------------------------
__global__ __launch_bounds__(256) void prep_all(const float* __restrict__ X,
                                                short* __restrict__ Xa,
                                                short* __restrict__ Aw,
                                                const float* __restrict__ Wa,
                                                const float* __restrict__ Wz,
                                                const float* __restrict__ theta,
                                                float* __restrict__ partials) {
    const int bid = blockIdx.x;
    const int t = threadIdx.x;

    if (bid < PREP_CONV) {
        // ---- convert_x: one block per row
        const int row = bid;
        const float4* xr = reinterpret_cast<const float4*>(X + (size_t)row * KX);
        float4 v0 = xr[t * 2];
        float4 v1 = xr[t * 2 + 1];
        bf16x8 s;
        s[0] = f2bf(v0.x); s[1] = f2bf(v0.y); s[2] = f2bf(v0.z); s[3] = f2bf(v0.w);
        s[4] = f2bf(v1.x); s[5] = f2bf(v1.y); s[6] = f2bf(v1.z); s[7] = f2bf(v1.w);
        short* outr = Xa + (size_t)row * KA;
        reinterpret_cast<bf16x8*>(outr)[t] = s;
        float sq = v0.x*v0.x + v0.y*v0.y + v0.z*v0.z + v0.w*v0.w
                 + v1.x*v1.x + v1.y*v1.y + v1.z*v1.z + v1.w*v1.w;
        sq += __shfl_xor(sq, 1);
        sq += __shfl_xor(sq, 2);
        if ((t & 3) == 0) outr[KX + (t >> 2)] = f2bf(sq - 32.0f);  // centered
    } else if (bid < PREP_A1) {
        // ---- build_a1: (8 k-blocks, 32 o-blocks)
        const int b = bid - PREP_CONV;
        const int k = (b & 7) * 256 + t;
        const int o0 = (b >> 3) * A1_OT;
        float wz[64];
#pragma unroll
        for (int d = 0; d < 64; ++d) wz[d] = Wz[(size_t)d * KX + k];
        for (int o = o0; o < o0 + A1_OT; ++o) {
            const float* war = Wa + (size_t)o * WCOLS;
            float acc = 0.f;
#pragma unroll
            for (int d = 0; d < 64; ++d) acc += war[d] * wz[d];
            Aw[(size_t)o * KA + k] = f2bf(acc);
        }
    } else {
        // ---- build_a2 partials: (8 chunks, 64 o-blocks)
        const int b = bid - PREP_A1;
        const int n = t & 63;
        const int g = t >> 6;
        const int chunk = b & 7;
        const int o0 = (b >> 3) * A2_OT;
        const int d0 = chunk * A2_DPC;
        float acc[A2_OT];
#pragma unroll
        for (int j = 0; j < A2_OT; ++j) acc[j] = 0.f;
        for (int i = g; i < A2_DPC; i += 4) {
            const int d = d0 + i;
            float th = theta[(size_t)d * NF + n];
            float th2 = th * th;
#pragma unroll
            for (int j = 0; j < A2_OT; ++j)
                acc[j] += Wa[(size_t)(o0 + j) * WCOLS + NF + d] * th2;
        }
        __shared__ float red[4][A2_OT][64];
#pragma unroll
        for (int j = 0; j < A2_OT; ++j) red[g][j][n] = acc[j];
        __syncthreads();
#pragma unroll
        for (int k2 = 0; k2 < A2_OT * 64 / 256; ++k2) {
            const int idx = t + k2 * 256;
            const int ol = idx >> 6, nn = idx & 63;
            float s = red[0][ol][nn] + red[1][ol][nn] + red[2][ol][nn] + red[3][ol][nn];
            partials[((size_t)chunk * ODIM + o0 + ol) * NF + nn] = s;
        }
    }
}

// Kernel 2: reduce A2_DC partials -> bf16 Aw cols [2048,2112)
__global__ __launch_bounds__(256) void a2_reduce(const float* __restrict__ partials,
                                                 short* __restrict__ Aw) {
    const int idx = blockIdx.x * 256 + threadIdx.x;   // o*64+n
    const int o = idx >> 6, n = idx & 63;
    float s = 0.f;
#pragma unroll
    for (int c = 0; c < A2_DC; ++c)
        s += partials[((size_t)c * ODIM + o) * NF + n];
    Aw[(size_t)o * KA + KX + n] = f2bf(s);
}

// ---------------------------------------------------------------------------
// Kernel 3: GEMM (round-2 proven single-buffer 2-barrier loop)
// + fused BN column sum/sumsq epilogue.  Bias dropped (cancels under BN).
// ---------------------------------------------------------------------------
__global__ __launch_bounds__(256) void gemm_kern(const short* __restrict__ Xa,
                                                 const short* __restrict__ Aw,
                                                 float* __restrict__ C,
                                                 float* __restrict__ sums) {
    __shared__ __align__(16) short As[128 * 32];
    __shared__ __align__(16) short Bs[128 * 32];
    const int tid  = threadIdx.x;
    const int lane = tid & 63;
    const int wid  = tid >> 6;
    const int wr = wid >> 1, wc = wid & 1;
    const int bm = blockIdx.x * 128;
    const int bn = blockIdx.y * 128;

    f32x4 acc[4][4] = {};

    // Staging: chunk c (16B) at LDS pos c holds global slot q = (c&3) ^ ((r>>1)&3)
    const int c0 = tid, c1 = tid + 256;
    const int r0 = c0 >> 2, q0 = (c0 & 3) ^ ((r0 >> 1) & 3);
    const int r1 = c1 >> 2, q1 = (c1 & 3) ^ ((r1 >> 1) & 3);
    const short* gA0 = Xa + (size_t)(bm + r0) * KA + q0 * 8;
    const short* gA1 = Xa + (size_t)(bm + r1) * KA + q1 * 8;
    const short* gB0 = Aw + (size_t)(bn + r0) * KA + q0 * 8;
    const short* gB1 = Aw + (size_t)(bn + r1) * KA + q1 * 8;
    short* lA0 = As + c0 * 8;  short* lA1 = As + c1 * 8;
    short* lB0 = Bs + c0 * 8;  short* lB1 = Bs + c1 * 8;

    // Swizzled LDS read offsets
    const int lq = lane >> 4;
    int offA[4], offB[4];
#pragma unroll
    for (int m = 0; m < 4; ++m) {
        int ra = wr * 64 + m * 16 + (lane & 15);
        offA[m] = ra * 32 + (lq ^ ((ra >> 1) & 3)) * 8;
        int rb = wc * 64 + m * 16 + (lane & 15);
        offB[m] = rb * 32 + (lq ^ ((rb >> 1) & 3)) * 8;
    }

    for (int kt = 0; kt < KA / 32; ++kt) {
        const int ko = kt * 32;
        gload16(gA0 + ko, lA0);
        gload16(gA1 + ko, lA1);
        gload16(gB0 + ko, lB0);
        gload16(gB1 + ko, lB1);
        __syncthreads();
        bf16x8 a[4], b[4];
#pragma unroll
        for (int m = 0; m < 4; ++m) a[m] = *reinterpret_cast<const bf16x8*>(As + offA[m]);
#pragma unroll
        for (int n = 0; n < 4; ++n) b[n] = *reinterpret_cast<const bf16x8*>(Bs + offB[n]);
#pragma unroll
        for (int m = 0; m < 4; ++m)
#pragma unroll
            for (int n = 0; n < 4; ++n)
                acc[m][n] = __builtin_amdgcn_mfma_f32_16x16x32_bf16(a[m], b[n], acc[m][n], 0, 0, 0);
        __syncthreads();
    }

    // Epilogue: store C (pre-BN) + fused column sum/sumsq partials.
    // C/D layout col=lane&15, row=(lane>>4)*4+reg (m89/m91 verified).
    const int rlo = (lane >> 4) * 4;
    const int cl  = lane & 15;
#pragma unroll
    for (int n = 0; n < 4; ++n) {
        const int col = bn + wc * 64 + n * 16 + cl;
        float s = 0.f, q = 0.f;
#pragma unroll
        for (int m = 0; m < 4; ++m) {
            const int rowb = bm + wr * 64 + m * 16 + rlo;
#pragma unroll
            for (int r2 = 0; r2 < 4; ++r2) {
                float v = acc[m][n][r2];
                C[(size_t)(rowb + r2) * ODIM + col] = v;
                s += v; q += v * v;
            }
        }
        s += __shfl_xor(s, 16); s += __shfl_xor(s, 32);
        q += __shfl_xor(q, 16); q += __shfl_xor(q, 32);
        if (lane < 16) {
            atomicAdd(&sums[col], s);
            atomicAdd(&sums[ODIM + col], q);
        }
    }
}

// ---------------------------------------------------------------------------
// Kernel 4: BN apply with inline finalize.  Thread owns one column-quad of
// 4 rows (row0, row0+2048, +4096, +6144); computes scale/shift once.
// Grid MUST be NROWS/4 * ODIM/4 / 256 = 2048 blocks (4 rows/thread!).
// ---------------------------------------------------------------------------
__global__ __launch_bounds__(256) void bn_apply(float* __restrict__ C,
                                                const float* __restrict__ sums,
                                                const float* __restrict__ gamma,
                                                const float* __restrict__ beta) {
    const int g = blockIdx.x * 256 + threadIdx.x;   // 524288 threads
    const int c4 = g & (ODIM / 4 - 1);              // column quad 0..255
    const int row0 = g >> 8;                        // 0..2047
    const float inv = 1.0f / (float)NROWS;
    float4 sc, sh;
    {
        float4 s0 = reinterpret_cast<const float4*>(sums)[c4];
        float4 q0 = reinterpret_cast<const float4*>(sums + ODIM)[c4];
        float4 gm = reinterpret_cast<const float4*>(gamma)[c4];
        float4 bt = reinterpret_cast<const float4*>(beta)[c4];
        float m, v;
        m = s0.x * inv; v = q0.x * inv - m * m; sc.x = gm.x * rsqrtf(v + BN_EPS); sh.x = bt.x - m * sc.x;
        m = s0.y * inv; v = q0.y * inv - m * m; sc.y = gm.y * rsqrtf(v + BN_EPS); sh.y = bt.y - m * sc.y;
        m = s0.z * inv; v = q0.z * inv - m * m; sc.z = gm.z * rsqrtf(v + BN_EPS); sh.z = bt.z - m * sc.z;
        m = s0.w * inv; v = q0.w * inv - m * m; sc.w = gm.w * rsqrtf(v + BN_EPS); sh.w = bt.w - m * sc.w;
    }
#pragma unroll
    for (int r = 0; r < 4; ++r) {
        const size_t i = (size_t)(row0 + r * 2048) * (ODIM / 4) + c4;
        float4 v = reinterpret_cast<const float4*>(C)[i];
        v.x = v.x * sc.x + sh.x;
        v.y = v.y * sc.y + sh.y;
        v.z = v.z * sc.z + sh.z;
        v.w = v.w * sc.w + sh.w;
        reinterpret_cast<float4*>(C)[i] = v;
    }
}

// ---------------------------------------------------------------------------
extern "C" void kernel_launch(void* const* d_in, const int* in_sizes, int n_in,
                              void* d_out, int out_size, void* d_ws, size_t ws_size,
                              hipStream_t stream) {
    const float* X     = (const float*)d_in[0];
    const float* Wz    = (const float*)d_in[1];
    const float* theta = (const float*)d_in[2];
    const float* Wa    = (const float*)d_in[3];
    const float* gamma = (const float*)d_in[5];
    const float* beta  = (const float*)d_in[6];
    float* out = (float*)d_out;

    char* ws = (char*)d_ws;
    float* sums = (float*)ws;                                        // 2*1024 f32
    short* Xa = (short*)(ws + 16384);                                // 8192*2112 bf16
    short* Aw = (short*)(ws + 16384 + (size_t)NROWS * KA * 2);       // 1024*2112 bf16
    float* partials = (float*)(ws + 16384 + (size_t)NROWS * KA * 2
                                        + (size_t)ODIM * KA * 2);    // 8*1024*64 f32

    hipMemsetAsync(sums, 0, 2 * ODIM * sizeof(float), stream);
    prep_all<<<PREP_A2, 256, 0, stream>>>(X, Xa, Aw, Wa, Wz, theta, partials);
    a2_reduce<<<ODIM * NF / 256, 256, 0, stream>>>(partials, Aw);
    gemm_kern<<<dim3(NROWS / 128, ODIM / 128), 256, 0, stream>>>(Xa, Aw, out, sums);
    // 4 rows per thread -> 2048 blocks (8192 was the round-5 OOB crash)
    bn_apply<<<NROWS / 4 * ODIM / 4 / 256, 256, 0, stream>>>(out, sums, gamma, beta);
}

// Round 7
// 112.642 us; speedup vs baseline: 1.6775x; 1.0408x over previous
//
#include <hip/hip_runtime.h>
#include <stdint.h>

#define NROWS 8192
#define KX    2048      // N*M
#define KA    2112      // KX + NF (augmented K)
#define NF    64
#define DD    2016
#define WCOLS 2080      // NF + DD
#define ODIM  1024
#define BN_EPS 1e-5f

#define A1_OT 32        // o-tile for build_a1
#define A2_DC 8         // d-chunks for build_a2
#define A2_DPC 252      // DD / A2_DC
#define A2_OT 16        // o-tile for build_a2

// prep grid layout: LONG blocks first (start at t=0), conv after.
// [0,256) a1 | [256,768) a2 | [768,768+8192) conv
#define PREP_A1N   256
#define PREP_A2N   512
#define PREP_CONV0 (PREP_A1N + PREP_A2N)
#define PREP_TOT   (PREP_CONV0 + NROWS)

using f32x4  = __attribute__((ext_vector_type(4))) float;
using bf16x8 = __attribute__((ext_vector_type(8))) short;

__device__ __forceinline__ short f2bf(float x) {
    uint32_t u = __float_as_uint(x);
    uint32_t r = (u + 0x7FFFu + ((u >> 16) & 1u)) >> 16;   // RNE to bf16
    return (short)r;
}

__device__ __forceinline__ void gload16(const void* g, void* l) {
    __builtin_amdgcn_global_load_lds(
        (const __attribute__((address_space(1))) uint32_t*)g,
        (__attribute__((address_space(3))) uint32_t*)l, 16, 0, 0);
}

// ---------------------------------------------------------------------------
// Kernel 1 (fused prep).  Long latency-bound branches (a1, a2) occupy the
// low block IDs so they start immediately; the 8192 BW-bound conv blocks
// fill the machine behind them.  Wa tiles are staged in LDS to replace
// per-iteration wave-uniform s_loads (latency chain) with LDS broadcasts.
// ---------------------------------------------------------------------------
__global__ __launch_bounds__(256) void prep_all(const float* __restrict__ X,
                                                short* __restrict__ Xa,
                                                short* __restrict__ Aw,
                                                const float* __restrict__ Wa,
                                                const float* __restrict__ Wz,
                                                const float* __restrict__ theta,
                                                float* __restrict__ partials) {
    const int bid = blockIdx.x;
    const int t = threadIdx.x;
    // manual union: a1 uses [0,2048); a2 uses [0,4032) WaTile + [4032,8128) red
    __shared__ __align__(16) float smem[8128];

    if (bid >= PREP_CONV0) {
        // ---- convert_x: one block per row
        const int row = bid - PREP_CONV0;
        const float4* xr = reinterpret_cast<const float4*>(X + (size_t)row * KX);
        float4 v0 = xr[t * 2];
        float4 v1 = xr[t * 2 + 1];
        bf16x8 s;
        s[0] = f2bf(v0.x); s[1] = f2bf(v0.y); s[2] = f2bf(v0.z); s[3] = f2bf(v0.w);
        s[4] = f2bf(v1.x); s[5] = f2bf(v1.y); s[6] = f2bf(v1.z); s[7] = f2bf(v1.w);
        short* outr = Xa + (size_t)row * KA;
        reinterpret_cast<bf16x8*>(outr)[t] = s;
        float sq = v0.x*v0.x + v0.y*v0.y + v0.z*v0.z + v0.w*v0.w
                 + v1.x*v1.x + v1.y*v1.y + v1.z*v1.z + v1.w*v1.w;
        sq += __shfl_xor(sq, 1);
        sq += __shfl_xor(sq, 2);
        if ((t & 3) == 0) outr[KX + (t >> 2)] = f2bf(sq - 32.0f);  // centered
    } else if (bid < PREP_A1N) {
        // ---- build_a1: (8 k-blocks, 32 o-blocks).  Wa tile (32x64) in LDS.
        const int b = bid;
        const int k = (b & 7) * 256 + t;
        const int o0 = (b >> 3) * A1_OT;
        for (int idx = t; idx < A1_OT * 64; idx += 256)
            smem[idx] = Wa[(size_t)(o0 + (idx >> 6)) * WCOLS + (idx & 63)];
        float wz[64];
#pragma unroll
        for (int d = 0; d < 64; ++d) wz[d] = Wz[(size_t)d * KX + k];
        __syncthreads();
#pragma unroll 2
        for (int j = 0; j < A1_OT; ++j) {
            const float* war = &smem[j * 64];
            float acc = 0.f;
#pragma unroll
            for (int d = 0; d < 64; ++d) acc += war[d] * wz[d];
            Aw[(size_t)(o0 + j) * KA + k] = f2bf(acc);
        }
    } else {
        // ---- build_a2 partials: (8 chunks, 64 o-blocks).  Wa tile in LDS.
        const int b = bid - PREP_A1N;
        const int n = t & 63;
        const int g = t >> 6;
        const int chunk = b & 7;
        const int o0 = (b >> 3) * A2_OT;
        const int d0 = chunk * A2_DPC;
        float* waT = smem;                       // [A2_OT][A2_DPC] = 4032
        float* red = smem + A2_OT * A2_DPC;      // [4][A2_OT][64]  = 4096
        for (int idx = t; idx < A2_OT * A2_DPC; idx += 256) {
            const int j = idx / A2_DPC, dd = idx - j * A2_DPC;
            waT[idx] = Wa[(size_t)(o0 + j) * WCOLS + NF + d0 + dd];
        }
        __syncthreads();
        float acc[A2_OT];
#pragma unroll
        for (int j = 0; j < A2_OT; ++j) acc[j] = 0.f;
        for (int i = g; i < A2_DPC; i += 4) {
            float th = theta[(size_t)(d0 + i) * NF + n];
            float th2 = th * th;
#pragma unroll
            for (int j = 0; j < A2_OT; ++j)
                acc[j] += waT[j * A2_DPC + i] * th2;
        }
#pragma unroll
        for (int j = 0; j < A2_OT; ++j) red[(g * A2_OT + j) * 64 + n] = acc[j];
        __syncthreads();
#pragma unroll
        for (int k2 = 0; k2 < A2_OT * 64 / 256; ++k2) {
            const int idx = t + k2 * 256;
            const int ol = idx >> 6, nn = idx & 63;
            float s = red[(0 * A2_OT + ol) * 64 + nn] + red[(1 * A2_OT + ol) * 64 + nn]
                    + red[(2 * A2_OT + ol) * 64 + nn] + red[(3 * A2_OT + ol) * 64 + nn];
            partials[((size_t)chunk * ODIM + o0 + ol) * NF + nn] = s;
        }
    }
}

// Kernel 2: reduce A2_DC partials -> bf16 Aw cols [2048,2112)
__global__ __launch_bounds__(256) void a2_reduce(const float* __restrict__ partials,
                                                 short* __restrict__ Aw) {
    const int idx = blockIdx.x * 256 + threadIdx.x;   // o*64+n
    const int o = idx >> 6, n = idx & 63;
    float s = 0.f;
#pragma unroll
    for (int c = 0; c < A2_DC; ++c)
        s += partials[((size_t)c * ODIM + o) * NF + n];
    Aw[(size_t)o * KA + KX + n] = f2bf(s);
}

// ---------------------------------------------------------------------------
// Kernel 3: GEMM (round-2 proven single-buffer 2-barrier loop)
// + fused BN column sum/sumsq epilogue.  Bias dropped (cancels under BN).
// ---------------------------------------------------------------------------
__global__ __launch_bounds__(256) void gemm_kern(const short* __restrict__ Xa,
                                                 const short* __restrict__ Aw,
                                                 float* __restrict__ C,
                                                 float* __restrict__ sums) {
    __shared__ __align__(16) short As[128 * 32];
    __shared__ __align__(16) short Bs[128 * 32];
    const int tid  = threadIdx.x;
    const int lane = tid & 63;
    const int wid  = tid >> 6;
    const int wr = wid >> 1, wc = wid & 1;
    const int bm = blockIdx.x * 128;
    const int bn = blockIdx.y * 128;

    f32x4 acc[4][4] = {};

    // Staging: chunk c (16B) at LDS pos c holds global slot q = (c&3) ^ ((r>>1)&3)
    const int c0 = tid, c1 = tid + 256;
    const int r0 = c0 >> 2, q0 = (c0 & 3) ^ ((r0 >> 1) & 3);
    const int r1 = c1 >> 2, q1 = (c1 & 3) ^ ((r1 >> 1) & 3);
    const short* gA0 = Xa + (size_t)(bm + r0) * KA + q0 * 8;
    const short* gA1 = Xa + (size_t)(bm + r1) * KA + q1 * 8;
    const short* gB0 = Aw + (size_t)(bn + r0) * KA + q0 * 8;
    const short* gB1 = Aw + (size_t)(bn + r1) * KA + q1 * 8;
    short* lA0 = As + c0 * 8;  short* lA1 = As + c1 * 8;
    short* lB0 = Bs + c0 * 8;  short* lB1 = Bs + c1 * 8;

    // Swizzled LDS read offsets
    const int lq = lane >> 4;
    int offA[4], offB[4];
#pragma unroll
    for (int m = 0; m < 4; ++m) {
        int ra = wr * 64 + m * 16 + (lane & 15);
        offA[m] = ra * 32 + (lq ^ ((ra >> 1) & 3)) * 8;
        int rb = wc * 64 + m * 16 + (lane & 15);
        offB[m] = rb * 32 + (lq ^ ((rb >> 1) & 3)) * 8;
    }

    for (int kt = 0; kt < KA / 32; ++kt) {
        const int ko = kt * 32;
        gload16(gA0 + ko, lA0);
        gload16(gA1 + ko, lA1);
        gload16(gB0 + ko, lB0);
        gload16(gB1 + ko, lB1);
        __syncthreads();
        bf16x8 a[4], b[4];
#pragma unroll
        for (int m = 0; m < 4; ++m) a[m] = *reinterpret_cast<const bf16x8*>(As + offA[m]);
#pragma unroll
        for (int n = 0; n < 4; ++n) b[n] = *reinterpret_cast<const bf16x8*>(Bs + offB[n]);
#pragma unroll
        for (int m = 0; m < 4; ++m)
#pragma unroll
            for (int n = 0; n < 4; ++n)
                acc[m][n] = __builtin_amdgcn_mfma_f32_16x16x32_bf16(a[m], b[n], acc[m][n], 0, 0, 0);
        __syncthreads();
    }

    // Epilogue: store C (pre-BN) + fused column sum/sumsq partials.
    // C/D layout col=lane&15, row=(lane>>4)*4+reg (m89/m91 verified).
    const int rlo = (lane >> 4) * 4;
    const int cl  = lane & 15;
#pragma unroll
    for (int n = 0; n < 4; ++n) {
        const int col = bn + wc * 64 + n * 16 + cl;
        float s = 0.f, q = 0.f;
#pragma unroll
        for (int m = 0; m < 4; ++m) {
            const int rowb = bm + wr * 64 + m * 16 + rlo;
#pragma unroll
            for (int r2 = 0; r2 < 4; ++r2) {
                float v = acc[m][n][r2];
                C[(size_t)(rowb + r2) * ODIM + col] = v;
                s += v; q += v * v;
            }
        }
        s += __shfl_xor(s, 16); s += __shfl_xor(s, 32);
        q += __shfl_xor(q, 16); q += __shfl_xor(q, 32);
        if (lane < 16) {
            atomicAdd(&sums[col], s);
            atomicAdd(&sums[ODIM + col], q);
        }
    }
}

// ---------------------------------------------------------------------------
// Kernel 4: BN apply with inline finalize.  Thread owns one column-quad of
// 4 rows (row0, row0+2048, +4096, +6144); computes scale/shift once.
// Grid MUST be NROWS/4 * ODIM/4 / 256 = 2048 blocks (4 rows/thread!).
// ---------------------------------------------------------------------------
__global__ __launch_bounds__(256) void bn_apply(float* __restrict__ C,
                                                const float* __restrict__ sums,
                                                const float* __restrict__ gamma,
                                                const float* __restrict__ beta) {
    const int g = blockIdx.x * 256 + threadIdx.x;   // 524288 threads
    const int c4 = g & (ODIM / 4 - 1);              // column quad 0..255
    const int row0 = g >> 8;                        // 0..2047
    const float inv = 1.0f / (float)NROWS;
    float4 sc, sh;
    {
        float4 s0 = reinterpret_cast<const float4*>(sums)[c4];
        float4 q0 = reinterpret_cast<const float4*>(sums + ODIM)[c4];
        float4 gm = reinterpret_cast<const float4*>(gamma)[c4];
        float4 bt = reinterpret_cast<const float4*>(beta)[c4];
        float m, v;
        m = s0.x * inv; v = q0.x * inv - m * m; sc.x = gm.x * rsqrtf(v + BN_EPS); sh.x = bt.x - m * sc.x;
        m = s0.y * inv; v = q0.y * inv - m * m; sc.y = gm.y * rsqrtf(v + BN_EPS); sh.y = bt.y - m * sc.y;
        m = s0.z * inv; v = q0.z * inv - m * m; sc.z = gm.z * rsqrtf(v + BN_EPS); sh.z = bt.z - m * sc.z;
        m = s0.w * inv; v = q0.w * inv - m * m; sc.w = gm.w * rsqrtf(v + BN_EPS); sh.w = bt.w - m * sc.w;
    }
#pragma unroll
    for (int r = 0; r < 4; ++r) {
        const size_t i = (size_t)(row0 + r * 2048) * (ODIM / 4) + c4;
        float4 v = reinterpret_cast<const float4*>(C)[i];
        v.x = v.x * sc.x + sh.x;
        v.y = v.y * sc.y + sh.y;
        v.z = v.z * sc.z + sh.z;
        v.w = v.w * sc.w + sh.w;
        reinterpret_cast<float4*>(C)[i] = v;
    }
}

// ---------------------------------------------------------------------------
extern "C" void kernel_launch(void* const* d_in, const int* in_sizes, int n_in,
                              void* d_out, int out_size, void* d_ws, size_t ws_size,
                              hipStream_t stream) {
    const float* X     = (const float*)d_in[0];
    const float* Wz    = (const float*)d_in[1];
    const float* theta = (const float*)d_in[2];
    const float* Wa    = (const float*)d_in[3];
    const float* gamma = (const float*)d_in[5];
    const float* beta  = (const float*)d_in[6];
    float* out = (float*)d_out;

    char* ws = (char*)d_ws;
    float* sums = (float*)ws;                                        // 2*1024 f32
    short* Xa = (short*)(ws + 16384);                                // 8192*2112 bf16
    short* Aw = (short*)(ws + 16384 + (size_t)NROWS * KA * 2);       // 1024*2112 bf16
    float* partials = (float*)(ws + 16384 + (size_t)NROWS * KA * 2
                                        + (size_t)ODIM * KA * 2);    // 8*1024*64 f32

    hipMemsetAsync(sums, 0, 2 * ODIM * sizeof(float), stream);
    prep_all<<<PREP_TOT, 256, 0, stream>>>(X, Xa, Aw, Wa, Wz, theta, partials);
    a2_reduce<<<ODIM * NF / 256, 256, 0, stream>>>(partials, Aw);
    gemm_kern<<<dim3(NROWS / 128, ODIM / 128), 256, 0, stream>>>(Xa, Aw, out, sums);
    // 4 rows per thread -> 2048 blocks (8192 was the round-5 OOB crash)
    bn_apply<<<NROWS / 4 * ODIM / 4 / 256, 256, 0, stream>>>(out, sums, gamma, beta);
}

// Round 8
// 110.029 us; speedup vs baseline: 1.7173x; 1.0237x over previous
//
#include <hip/hip_runtime.h>
#include <stdint.h>

#define NROWS 8192
#define KX    2048      // N*M
#define KA    2112      // KX + NF (augmented K)
#define NF    64
#define DD    2016
#define WCOLS 2080      // NF + DD
#define ODIM  1024
#define BN_EPS 1e-5f

#define A1_OT 32        // o-tile for build_a1
#define A2_DC 8         // d-chunks for build_a2
#define A2_DPC 252      // DD / A2_DC
#define A2_OT 16        // o-tile for build_a2

#define CONV_RPB 4      // rows per conv block (fat blocks beat launch-rate floor)
#define CONV_NB  (NROWS / CONV_RPB)   // 2048

// prep grid layout: long blocks first, conv after.
// [0,256) a1 | [256,768) a2 | [768,768+2048) conv
#define PREP_A1N   256
#define PREP_A2N   512
#define PREP_CONV0 (PREP_A1N + PREP_A2N)
#define PREP_TOT   (PREP_CONV0 + CONV_NB)

using f32x4  = __attribute__((ext_vector_type(4))) float;
using bf16x8 = __attribute__((ext_vector_type(8))) short;

__device__ __forceinline__ short f2bf(float x) {
    uint32_t u = __float_as_uint(x);
    uint32_t r = (u + 0x7FFFu + ((u >> 16) & 1u)) >> 16;   // RNE to bf16
    return (short)r;
}

__device__ __forceinline__ void gload16(const void* g, void* l) {
    __builtin_amdgcn_global_load_lds(
        (const __attribute__((address_space(1))) uint32_t*)g,
        (__attribute__((address_space(3))) uint32_t*)l, 16, 0, 0);
}

// ---------------------------------------------------------------------------
// Kernel 1 (fused prep).
//  conv: 2048 blocks x 4 rows — fat blocks; 8192x1 was launch-rate-bound
//        (round-7 PMC: 18% occupancy, 1.3 TB/s, 60 us).
//  a1/a2: LDS-staged Wa, low block IDs (start early).
// ---------------------------------------------------------------------------
__global__ __launch_bounds__(256) void prep_all(const float* __restrict__ X,
                                                short* __restrict__ Xa,
                                                short* __restrict__ Aw,
                                                const float* __restrict__ Wa,
                                                const float* __restrict__ Wz,
                                                const float* __restrict__ theta,
                                                float* __restrict__ partials) {
    const int bid = blockIdx.x;
    const int t = threadIdx.x;
    // manual union: a1 uses [0,2048); a2 uses [0,4032) WaTile + [4032,8128) red
    __shared__ __align__(16) float smem[8128];

    if (bid >= PREP_CONV0) {
        // ---- convert_x: 4 consecutive rows per block
        const int b = bid - PREP_CONV0;
        for (int r = 0; r < CONV_RPB; ++r) {
            const int row = b * CONV_RPB + r;
            const float4* xr = reinterpret_cast<const float4*>(X + (size_t)row * KX);
            float4 v0 = xr[t * 2];
            float4 v1 = xr[t * 2 + 1];
            bf16x8 s;
            s[0] = f2bf(v0.x); s[1] = f2bf(v0.y); s[2] = f2bf(v0.z); s[3] = f2bf(v0.w);
            s[4] = f2bf(v1.x); s[5] = f2bf(v1.y); s[6] = f2bf(v1.z); s[7] = f2bf(v1.w);
            short* outr = Xa + (size_t)row * KA;
            reinterpret_cast<bf16x8*>(outr)[t] = s;
            float sq = v0.x*v0.x + v0.y*v0.y + v0.z*v0.z + v0.w*v0.w
                     + v1.x*v1.x + v1.y*v1.y + v1.z*v1.z + v1.w*v1.w;
            sq += __shfl_xor(sq, 1);
            sq += __shfl_xor(sq, 2);
            if ((t & 3) == 0) outr[KX + (t >> 2)] = f2bf(sq - 32.0f);  // centered
        }
    } else if (bid < PREP_A1N) {
        // ---- build_a1: (8 k-blocks, 32 o-blocks).  Wa tile (32x64) in LDS.
        const int b = bid;
        const int k = (b & 7) * 256 + t;
        const int o0 = (b >> 3) * A1_OT;
        for (int idx = t; idx < A1_OT * 64; idx += 256)
            smem[idx] = Wa[(size_t)(o0 + (idx >> 6)) * WCOLS + (idx & 63)];
        float wz[64];
#pragma unroll
        for (int d = 0; d < 64; ++d) wz[d] = Wz[(size_t)d * KX + k];
        __syncthreads();
#pragma unroll 2
        for (int j = 0; j < A1_OT; ++j) {
            const float* war = &smem[j * 64];
            float acc = 0.f;
#pragma unroll
            for (int d = 0; d < 64; ++d) acc += war[d] * wz[d];
            Aw[(size_t)(o0 + j) * KA + k] = f2bf(acc);
        }
    } else {
        // ---- build_a2 partials: (8 chunks, 64 o-blocks).  Wa tile in LDS.
        const int b = bid - PREP_A1N;
        const int n = t & 63;
        const int g = t >> 6;
        const int chunk = b & 7;
        const int o0 = (b >> 3) * A2_OT;
        const int d0 = chunk * A2_DPC;
        float* waT = smem;                       // [A2_OT][A2_DPC] = 4032
        float* red = smem + A2_OT * A2_DPC;      // [4][A2_OT][64]  = 4096
        for (int idx = t; idx < A2_OT * A2_DPC; idx += 256) {
            const int j = idx / A2_DPC, dd = idx - j * A2_DPC;
            waT[idx] = Wa[(size_t)(o0 + j) * WCOLS + NF + d0 + dd];
        }
        __syncthreads();
        float acc[A2_OT];
#pragma unroll
        for (int j = 0; j < A2_OT; ++j) acc[j] = 0.f;
        for (int i = g; i < A2_DPC; i += 4) {
            float th = theta[(size_t)(d0 + i) * NF + n];
            float th2 = th * th;
#pragma unroll
            for (int j = 0; j < A2_OT; ++j)
                acc[j] += waT[j * A2_DPC + i] * th2;
        }
#pragma unroll
        for (int j = 0; j < A2_OT; ++j) red[(g * A2_OT + j) * 64 + n] = acc[j];
        __syncthreads();
#pragma unroll
        for (int k2 = 0; k2 < A2_OT * 64 / 256; ++k2) {
            const int idx = t + k2 * 256;
            const int ol = idx >> 6, nn = idx & 63;
            float s = red[(0 * A2_OT + ol) * 64 + nn] + red[(1 * A2_OT + ol) * 64 + nn]
                    + red[(2 * A2_OT + ol) * 64 + nn] + red[(3 * A2_OT + ol) * 64 + nn];
            partials[((size_t)chunk * ODIM + o0 + ol) * NF + nn] = s;
        }
    }
}

// Kernel 2: reduce A2_DC partials -> bf16 Aw cols [2048,2112)
__global__ __launch_bounds__(256) void a2_reduce(const float* __restrict__ partials,
                                                 short* __restrict__ Aw) {
    const int idx = blockIdx.x * 256 + threadIdx.x;   // o*64+n
    const int o = idx >> 6, n = idx & 63;
    float s = 0.f;
#pragma unroll
    for (int c = 0; c < A2_DC; ++c)
        s += partials[((size_t)c * ODIM + o) * NF + n];
    Aw[(size_t)o * KA + KX + n] = f2bf(s);
}

// ---------------------------------------------------------------------------
// Kernel 3: GEMM (round-2 proven single-buffer 2-barrier loop)
// + fused BN column sum/sumsq epilogue.  Bias dropped (cancels under BN).
// ---------------------------------------------------------------------------
__global__ __launch_bounds__(256) void gemm_kern(const short* __restrict__ Xa,
                                                 const short* __restrict__ Aw,
                                                 float* __restrict__ C,
                                                 float* __restrict__ sums) {
    __shared__ __align__(16) short As[128 * 32];
    __shared__ __align__(16) short Bs[128 * 32];
    const int tid  = threadIdx.x;
    const int lane = tid & 63;
    const int wid  = tid >> 6;
    const int wr = wid >> 1, wc = wid & 1;
    const int bm = blockIdx.x * 128;
    const int bn = blockIdx.y * 128;

    f32x4 acc[4][4] = {};

    // Staging: chunk c (16B) at LDS pos c holds global slot q = (c&3) ^ ((r>>1)&3)
    const int c0 = tid, c1 = tid + 256;
    const int r0 = c0 >> 2, q0 = (c0 & 3) ^ ((r0 >> 1) & 3);
    const int r1 = c1 >> 2, q1 = (c1 & 3) ^ ((r1 >> 1) & 3);
    const short* gA0 = Xa + (size_t)(bm + r0) * KA + q0 * 8;
    const short* gA1 = Xa + (size_t)(bm + r1) * KA + q1 * 8;
    const short* gB0 = Aw + (size_t)(bn + r0) * KA + q0 * 8;
    const short* gB1 = Aw + (size_t)(bn + r1) * KA + q1 * 8;
    short* lA0 = As + c0 * 8;  short* lA1 = As + c1 * 8;
    short* lB0 = Bs + c0 * 8;  short* lB1 = Bs + c1 * 8;

    // Swizzled LDS read offsets
    const int lq = lane >> 4;
    int offA[4], offB[4];
#pragma unroll
    for (int m = 0; m < 4; ++m) {
        int ra = wr * 64 + m * 16 + (lane & 15);
        offA[m] = ra * 32 + (lq ^ ((ra >> 1) & 3)) * 8;
        int rb = wc * 64 + m * 16 + (lane & 15);
        offB[m] = rb * 32 + (lq ^ ((rb >> 1) & 3)) * 8;
    }

    for (int kt = 0; kt < KA / 32; ++kt) {
        const int ko = kt * 32;
        gload16(gA0 + ko, lA0);
        gload16(gA1 + ko, lA1);
        gload16(gB0 + ko, lB0);
        gload16(gB1 + ko, lB1);
        __syncthreads();
        bf16x8 a[4], b[4];
#pragma unroll
        for (int m = 0; m < 4; ++m) a[m] = *reinterpret_cast<const bf16x8*>(As + offA[m]);
#pragma unroll
        for (int n = 0; n < 4; ++n) b[n] = *reinterpret_cast<const bf16x8*>(Bs + offB[n]);
#pragma unroll
        for (int m = 0; m < 4; ++m)
#pragma unroll
            for (int n = 0; n < 4; ++n)
                acc[m][n] = __builtin_amdgcn_mfma_f32_16x16x32_bf16(a[m], b[n], acc[m][n], 0, 0, 0);
        __syncthreads();
    }

    // Epilogue: store C (pre-BN) + fused column sum/sumsq partials.
    // C/D layout col=lane&15, row=(lane>>4)*4+reg (m89/m91 verified).
    const int rlo = (lane >> 4) * 4;
    const int cl  = lane & 15;
#pragma unroll
    for (int n = 0; n < 4; ++n) {
        const int col = bn + wc * 64 + n * 16 + cl;
        float s = 0.f, q = 0.f;
#pragma unroll
        for (int m = 0; m < 4; ++m) {
            const int rowb = bm + wr * 64 + m * 16 + rlo;
#pragma unroll
            for (int r2 = 0; r2 < 4; ++r2) {
                float v = acc[m][n][r2];
                C[(size_t)(rowb + r2) * ODIM + col] = v;
                s += v; q += v * v;
            }
        }
        s += __shfl_xor(s, 16); s += __shfl_xor(s, 32);
        q += __shfl_xor(q, 16); q += __shfl_xor(q, 32);
        if (lane < 16) {
            atomicAdd(&sums[col], s);
            atomicAdd(&sums[ODIM + col], q);
        }
    }
}

// ---------------------------------------------------------------------------
// Kernel 4: BN apply with inline finalize.  Thread owns one column-quad of
// 4 rows (row0, row0+2048, +4096, +6144); computes scale/shift once.
// Grid MUST be NROWS/4 * ODIM/4 / 256 = 2048 blocks (4 rows/thread!).
// ---------------------------------------------------------------------------
__global__ __launch_bounds__(256) void bn_apply(float* __restrict__ C,
                                                const float* __restrict__ sums,
                                                const float* __restrict__ gamma,
                                                const float* __restrict__ beta) {
    const int g = blockIdx.x * 256 + threadIdx.x;   // 524288 threads
    const int c4 = g & (ODIM / 4 - 1);              // column quad 0..255
    const int row0 = g >> 8;                        // 0..2047
    const float inv = 1.0f / (float)NROWS;
    float4 sc, sh;
    {
        float4 s0 = reinterpret_cast<const float4*>(sums)[c4];
        float4 q0 = reinterpret_cast<const float4*>(sums + ODIM)[c4];
        float4 gm = reinterpret_cast<const float4*>(gamma)[c4];
        float4 bt = reinterpret_cast<const float4*>(beta)[c4];
        float m, v;
        m = s0.x * inv; v = q0.x * inv - m * m; sc.x = gm.x * rsqrtf(v + BN_EPS); sh.x = bt.x - m * sc.x;
        m = s0.y * inv; v = q0.y * inv - m * m; sc.y = gm.y * rsqrtf(v + BN_EPS); sh.y = bt.y - m * sc.y;
        m = s0.z * inv; v = q0.z * inv - m * m; sc.z = gm.z * rsqrtf(v + BN_EPS); sh.z = bt.z - m * sc.z;
        m = s0.w * inv; v = q0.w * inv - m * m; sc.w = gm.w * rsqrtf(v + BN_EPS); sh.w = bt.w - m * sc.w;
    }
#pragma unroll
    for (int r = 0; r < 4; ++r) {
        const size_t i = (size_t)(row0 + r * 2048) * (ODIM / 4) + c4;
        float4 v = reinterpret_cast<const float4*>(C)[i];
        v.x = v.x * sc.x + sh.x;
        v.y = v.y * sc.y + sh.y;
        v.z = v.z * sc.z + sh.z;
        v.w = v.w * sc.w + sh.w;
        reinterpret_cast<float4*>(C)[i] = v;
    }
}

// ---------------------------------------------------------------------------
extern "C" void kernel_launch(void* const* d_in, const int* in_sizes, int n_in,
                              void* d_out, int out_size, void* d_ws, size_t ws_size,
                              hipStream_t stream) {
    const float* X     = (const float*)d_in[0];
    const float* Wz    = (const float*)d_in[1];
    const float* theta = (const float*)d_in[2];
    const float* Wa    = (const float*)d_in[3];
    const float* gamma = (const float*)d_in[5];
    const float* beta  = (const float*)d_in[6];
    float* out = (float*)d_out;

    char* ws = (char*)d_ws;
    float* sums = (float*)ws;                                        // 2*1024 f32
    short* Xa = (short*)(ws + 16384);                                // 8192*2112 bf16
    short* Aw = (short*)(ws + 16384 + (size_t)NROWS * KA * 2);       // 1024*2112 bf16
    float* partials = (float*)(ws + 16384 + (size_t)NROWS * KA * 2
                                        + (size_t)ODIM * KA * 2);    // 8*1024*64 f32

    hipMemsetAsync(sums, 0, 2 * ODIM * sizeof(float), stream);
    prep_all<<<PREP_TOT, 256, 0, stream>>>(X, Xa, Aw, Wa, Wz, theta, partials);
    a2_reduce<<<ODIM * NF / 256, 256, 0, stream>>>(partials, Aw);
    gemm_kern<<<dim3(NROWS / 128, ODIM / 128), 256, 0, stream>>>(Xa, Aw, out, sums);
    // 4 rows per thread -> 2048 blocks (8192 was the round-5 OOB crash)
    bn_apply<<<NROWS / 4 * ODIM / 4 / 256, 256, 0, stream>>>(out, sums, gamma, beta);
}